// Round 8
// baseline (487.594 us; speedup 1.0000x reference)
//
#include <hip/hip_runtime.h>

// Problem constants (from reference setup_inputs)
#define B_  4
#define H_  64
#define W_  64
#define C_  16
#define F_  32

#define NWE (8 * 9 * F_)   // 2304 float4 weight entries = 36864 B LDS

// Block = 256 thr = 4 waves = quarter of one output row (16 px).
// Wave = 4-px strip. Lane = (g, f): g = lane>>5 selects channel half (g=0: ch 0-7,
// g=1: ch 8-15); each lane computes ALL 4 px x 4 rotations partial-summed over its
// 8 channels; cross-half reduce via shfl_xor(32) at the end.
// One ds_read_b128 fetches DIFFERENT weights per half -> weight DS traffic halved
// vs ps-split (36 b128/wave total). x comes from global/L1 (2 addrs/wave, 12.7 KB
// row working set), all-immediate offsets from 3 row pointers.
// All 4 P4 rotations from one patch via compile-time permutation (rounds 3-6).
__global__ __launch_bounds__(256, 4) void mtp_main(const float* __restrict__ x,
                                                   const float* __restrict__ kern,
                                                   const float* __restrict__ tker,
                                                   float* __restrict__ out) {
    __shared__ float4 wlds[NWE];

    const int tid  = threadIdx.x;
    const int bidx = blockIdx.x;                 // (b*64 + i)*4 + qtr
    const int qtr  = bidx & 3;
    const int i    = (bidx >> 2) & 63;
    const int b    = bidx >> 8;

    // ---- stage weights: entry e = (ccp*9 + q)*32 + f -> (t_c0, t_c1, k_c0, k_c1)
    // (ccp = channel pair 0..7). Coalesced: consecutive threads = consecutive f.
    #pragma unroll
    for (int e0 = 0; e0 < 9; ++e0) {
        int e   = e0 * 256 + tid;                // 2304 = 9*256 exactly
        int f   = e & 31;
        int t   = e >> 5;
        int q   = t % 9;
        int ccp = t / 9;
        int s0 = (q * C_ + ccp * 2 + 0) * F_ + f;
        int s1 = (q * C_ + ccp * 2 + 1) * F_ + f;
        wlds[e] = make_float4(tker[s0], tker[s1], kern[s0], kern[s1]);
    }
    __syncthreads();

    const int lane = tid & 63;
    const int f    = lane & 31;
    const int g    = lane >> 5;                  // channel-group half
    const int w    = tid >> 6;                   // wave 0..3
    const int jb   = qtr * 16 + w * 4;           // strip base column

    const bool okL = (jb > 0);                   // halo col jb-1 valid?
    const bool okR = (jb + 4 < 64);              // halo col jb+4 valid?
    const bool ok0 = (i > 0);
    const bool ok2 = (i < 63);
    const int colL = okL ? (jb - 1) : 0;
    const int colR = okR ? (jb + 4) : 63;

    // row base pointers, channel-half folded in; rows clamped (zeroed later)
    const float* rp[3];
    rp[0] = x + ((b * H_ + (ok0 ? i - 1 : 0)) * W_) * C_ + g * 8;
    rp[1] = x + ((b * H_ + i) * W_) * C_ + g * 8;
    rp[2] = x + ((b * H_ + (ok2 ? i + 1 : 0)) * W_) * C_ + g * 8;

    float acc[4][4];                             // [px][r] partial over 8 channels
    #pragma unroll
    for (int px = 0; px < 4; ++px)
        #pragma unroll
        for (int r = 0; r < 4; ++r) acc[px][r] = 0.f;

    const int wbase = g * (4 * 9 * F_) + f;      // float4-entry index base

    #pragma unroll
    for (int it = 0; it < 4; ++it) {             // 4 channel-pairs of this half
        // weights: 9 ds_read_b128; halves read different ccp -> no broadcast waste
        float4 wq[9];
        #pragma unroll
        for (int q = 0; q < 9; ++q)
            wq[q] = wlds[wbase + (it * 9 + q) * F_];

        // x halo: 3 rows x 6 cols float2 (this lane's channel pair)
        float2 xh[3][6];
        #pragma unroll
        for (int dr = 0; dr < 3; ++dr) {
            const float* rb = rp[dr];
            xh[dr][0] = *reinterpret_cast<const float2*>(rb + colL * C_ + it * 2);
            #pragma unroll
            for (int lc = 1; lc <= 4; ++lc)
                xh[dr][lc] = *reinterpret_cast<const float2*>(rb + (jb - 1 + lc) * C_ + it * 2);
            xh[dr][5] = *reinterpret_cast<const float2*>(rb + colR * C_ + it * 2);
        }
        const float2 z2 = make_float2(0.f, 0.f);
        if (!okL) { xh[0][0] = z2; xh[1][0] = z2; xh[2][0] = z2; }   // wave-uniform
        if (!okR) { xh[0][5] = z2; xh[1][5] = z2; xh[2][5] = z2; }
        if (!ok0) {
            for (int lc = 0; lc < 6; ++lc) xh[0][lc] = z2;           // block-uniform
        }
        if (!ok2) {
            for (int lc = 0; lc < 6; ++lc) xh[2][lc] = z2;
        }

        #pragma unroll
        for (int px = 0; px < 4; ++px) {
            #pragma unroll
            for (int r = 0; r < 4; ++r) {
                float z0[9], z1[9];
                #pragma unroll
                for (int q = 0; q < 9; ++q) {
                    const int a = q / 3, bq = q % 3;
                    int di, dj;
                    switch (r) {   // x position = rot_r^{-1}(weight position q)
                        case 0:  di = a;      dj = bq;     break;
                        case 1:  di = 2 - bq; dj = a;      break;
                        case 2:  di = 2 - a;  dj = 2 - bq; break;
                        default: di = bq;     dj = 2 - a;  break;
                    }
                    const float2 xv = xh[di][px + dj];
                    z0[q] = fmaf(xv.x, wq[q].x, wq[q].z);
                    z1[q] = fmaf(xv.y, wq[q].y, wq[q].w);
                }
                float m0 = fmaxf(fmaxf(fmaxf(z0[0], z0[1]), z0[2]),
                           fmaxf(fmaxf(fmaxf(z0[3], z0[4]), z0[5]),
                                 fmaxf(fmaxf(z0[6], z0[7]), z0[8])));
                float m1 = fmaxf(fmaxf(fmaxf(z1[0], z1[1]), z1[2]),
                           fmaxf(fmaxf(fmaxf(z1[3], z1[4]), z1[5]),
                                 fmaxf(fmaxf(z1[6], z1[7]), z1[8])));
                acc[px][r] += m0 + m1;
            }
        }
    }

    // ---- cross-half reduce: total = (ch 0-7 partial) + (ch 8-15 partial)
    float tot[4][4];
    #pragma unroll
    for (int px = 0; px < 4; ++px)
        #pragma unroll
        for (int r = 0; r < 4; ++r)
            tot[px][r] = acc[px][r] + __shfl_xor(acc[px][r], 32, 64);

    // ---- store: per (r,pp) lane writes px = pp*2 + g -> 256B contiguous/inst.
    // Constant-index ternary (not tot[pp*2+g]) to avoid scratch (dyn-index trap).
    #pragma unroll
    for (int r = 0; r < 4; ++r) {
        float* op = out + ((((b * 4 + r) * H_ + i) * W_ + jb + g) * F_ + f);
        float v0 = g ? tot[1][r] : tot[0][r];
        float v1 = g ? tot[3][r] : tot[2][r];
        op[0]      = v0;
        op[2 * F_] = v1;
    }
}

extern "C" void kernel_launch(void* const* d_in, const int* in_sizes, int n_in,
                              void* d_out, int out_size, void* d_ws, size_t ws_size,
                              hipStream_t stream) {
    const float* x    = (const float*)d_in[0];
    const float* kern = (const float*)d_in[1];
    const float* tker = (const float*)d_in[2];
    float* out = (float*)d_out;

    hipLaunchKernelGGL(mtp_main, dim3(B_ * H_ * 4), dim3(256), 0, stream,
                       x, kern, tker, out);
}

// Round 9
// 24.283 us; speedup vs baseline: 20.0792x; 20.0792x over previous
//
#include <hip/hip_runtime.h>

// Problem constants (from reference setup_inputs)
#define B_  4
#define H_  64
#define W_  64
#define C_  16
#define F_  32

#define NWE (8 * 9 * F_)   // 2304 float4 weight entries = 36864 B LDS

// Block = 256 thr = 4 waves = quarter of one output row (16 px).
// Wave = 4-px strip. Lane = (g, f): g = lane>>5 selects channel half (g=0: ch 0-7,
// g=1: ch 8-15); each lane computes ALL 4 px x 4 rotations partial-summed over its
// 8 channels; cross-half reduce via shfl_xor(32) at the end.
// One ds_read_b128 fetches DIFFERENT weights per half -> weight DS traffic halved
// vs ps-split (36 b128/wave total). x comes from global/L1 (2 addrs/wave, 12.7 KB
// row working set), all-immediate offsets from 3 row pointers.
// All 4 P4 rotations from one patch via compile-time permutation (rounds 3-6).
//
// r8 lesson: full-unrolling the it-loop + launch_bounds min-waves floor = spill
// catastrophe (VGPR capped 64, 1.7 GB scratch). it-loop MUST be unroll 1; no
// occupancy floor in launch_bounds.
__global__ __launch_bounds__(256) void mtp_main(const float* __restrict__ x,
                                                const float* __restrict__ kern,
                                                const float* __restrict__ tker,
                                                float* __restrict__ out) {
    __shared__ float4 wlds[NWE];

    const int tid  = threadIdx.x;
    const int bidx = blockIdx.x;                 // (b*64 + i)*4 + qtr
    const int qtr  = bidx & 3;
    const int i    = (bidx >> 2) & 63;
    const int b    = bidx >> 8;

    // ---- stage weights: entry e = (ccp*9 + q)*32 + f -> (t_c0, t_c1, k_c0, k_c1)
    // (ccp = channel pair 0..7). Coalesced: consecutive threads = consecutive f.
    #pragma unroll
    for (int e0 = 0; e0 < 9; ++e0) {
        int e   = e0 * 256 + tid;                // 2304 = 9*256 exactly
        int f   = e & 31;
        int t   = e >> 5;
        int q   = t % 9;
        int ccp = t / 9;
        int s0 = (q * C_ + ccp * 2 + 0) * F_ + f;
        int s1 = (q * C_ + ccp * 2 + 1) * F_ + f;
        wlds[e] = make_float4(tker[s0], tker[s1], kern[s0], kern[s1]);
    }
    __syncthreads();

    const int lane = tid & 63;
    const int f    = lane & 31;
    const int g    = lane >> 5;                  // channel-group half
    const int w    = tid >> 6;                   // wave 0..3
    const int jb   = qtr * 16 + w * 4;           // strip base column

    const bool okL = (jb > 0);                   // halo col jb-1 valid?
    const bool okR = (jb + 4 < 64);              // halo col jb+4 valid?
    const bool ok0 = (i > 0);
    const bool ok2 = (i < 63);
    const int colL = okL ? (jb - 1) : 0;
    const int colR = okR ? (jb + 4) : 63;

    // row base pointers, channel-half folded in; rows clamped (zeroed later)
    const float* rp0 = x + ((b * H_ + (ok0 ? i - 1 : 0)) * W_) * C_ + g * 8;
    const float* rp1 = x + ((b * H_ + i) * W_) * C_ + g * 8;
    const float* rp2 = x + ((b * H_ + (ok2 ? i + 1 : 0)) * W_) * C_ + g * 8;

    float acc[4][4];                             // [px][r] partial over 8 channels
    #pragma unroll
    for (int px = 0; px < 4; ++px)
        #pragma unroll
        for (int r = 0; r < 4; ++r) acc[px][r] = 0.f;

    const int wbase = g * (4 * 9 * F_) + f;      // float4-entry index base

    #pragma unroll 1
    for (int it = 0; it < 4; ++it) {             // 4 channel-pairs of this half
        // weights: 9 ds_read_b128; halves read different ccp -> no broadcast waste
        float4 wq[9];
        #pragma unroll
        for (int q = 0; q < 9; ++q)
            wq[q] = wlds[wbase + (it * 9 + q) * F_];

        // x halo: 3 rows x 6 cols float2 (this lane's channel pair)
        float2 xh[3][6];
        #pragma unroll
        for (int dr = 0; dr < 3; ++dr) {
            const float* rb = (dr == 0) ? rp0 : (dr == 1) ? rp1 : rp2;
            xh[dr][0] = *reinterpret_cast<const float2*>(rb + colL * C_ + it * 2);
            #pragma unroll
            for (int lc = 1; lc <= 4; ++lc)
                xh[dr][lc] = *reinterpret_cast<const float2*>(rb + (jb - 1 + lc) * C_ + it * 2);
            xh[dr][5] = *reinterpret_cast<const float2*>(rb + colR * C_ + it * 2);
        }
        const float2 z2 = make_float2(0.f, 0.f);
        if (!okL) { xh[0][0] = z2; xh[1][0] = z2; xh[2][0] = z2; }   // wave-uniform
        if (!okR) { xh[0][5] = z2; xh[1][5] = z2; xh[2][5] = z2; }
        if (!ok0) {
            for (int lc = 0; lc < 6; ++lc) xh[0][lc] = z2;           // block-uniform
        }
        if (!ok2) {
            for (int lc = 0; lc < 6; ++lc) xh[2][lc] = z2;
        }

        #pragma unroll
        for (int px = 0; px < 4; ++px) {
            #pragma unroll
            for (int r = 0; r < 4; ++r) {
                float z0[9], z1[9];
                #pragma unroll
                for (int q = 0; q < 9; ++q) {
                    const int a = q / 3, bq = q % 3;
                    int di, dj;
                    switch (r) {   // x position = rot_r^{-1}(weight position q)
                        case 0:  di = a;      dj = bq;     break;
                        case 1:  di = 2 - bq; dj = a;      break;
                        case 2:  di = 2 - a;  dj = 2 - bq; break;
                        default: di = bq;     dj = 2 - a;  break;
                    }
                    const float2 xv = xh[di][px + dj];
                    z0[q] = fmaf(xv.x, wq[q].x, wq[q].z);
                    z1[q] = fmaf(xv.y, wq[q].y, wq[q].w);
                }
                float m0 = fmaxf(fmaxf(fmaxf(z0[0], z0[1]), z0[2]),
                           fmaxf(fmaxf(fmaxf(z0[3], z0[4]), z0[5]),
                                 fmaxf(fmaxf(z0[6], z0[7]), z0[8])));
                float m1 = fmaxf(fmaxf(fmaxf(z1[0], z1[1]), z1[2]),
                           fmaxf(fmaxf(fmaxf(z1[3], z1[4]), z1[5]),
                                 fmaxf(fmaxf(z1[6], z1[7]), z1[8])));
                acc[px][r] += m0 + m1;
            }
        }
    }

    // ---- cross-half reduce: total = (ch 0-7 partial) + (ch 8-15 partial)
    float tot[4][4];
    #pragma unroll
    for (int px = 0; px < 4; ++px)
        #pragma unroll
        for (int r = 0; r < 4; ++r)
            tot[px][r] = acc[px][r] + __shfl_xor(acc[px][r], 32, 64);

    // ---- store: per (r,slot) lane writes px = slot*2 + g -> 256B contiguous/inst.
    // Constant-index ternary (not tot[slot*2+g]) to avoid scratch (dyn-index trap).
    #pragma unroll
    for (int r = 0; r < 4; ++r) {
        float* op = out + ((((b * 4 + r) * H_ + i) * W_ + jb + g) * F_ + f);
        float v0 = g ? tot[1][r] : tot[0][r];
        float v1 = g ? tot[3][r] : tot[2][r];
        op[0]      = v0;
        op[2 * F_] = v1;
    }
}

extern "C" void kernel_launch(void* const* d_in, const int* in_sizes, int n_in,
                              void* d_out, int out_size, void* d_ws, size_t ws_size,
                              hipStream_t stream) {
    const float* x    = (const float*)d_in[0];
    const float* kern = (const float*)d_in[1];
    const float* tker = (const float*)d_in[2];
    float* out = (float*)d_out;

    hipLaunchKernelGGL(mtp_main, dim3(B_ * H_ * 4), dim3(256), 0, stream,
                       x, kern, tker, out);
}

// Round 10
// 21.282 us; speedup vs baseline: 22.9113x; 1.1410x over previous
//
#include <hip/hip_runtime.h>

// Problem constants (from reference setup_inputs)
#define B_  4
#define H_  64
#define W_  64
#define C_  16
#define F_  32

#define NWE (8 * 9 * F_)   // 2304 float4 weight entries = 36864 B
#define NXE (3 * 34 * 4)   // 408 float4 x-stage chunks   =  6528 B

// Round-10 design = r5 (all-LDS, 512-thr block = (b,i,half-row), 3 blocks/CU)
//                 + r9 (g-split: lane = (g, f), g = channel half).
// Wave = 4-px strip; each lane partial-sums its 8 channels over all 4 px x 4
// rotations; cross-half reduce via shfl_xor(32). One ds_read_b128 fetches
// DIFFERENT weights per 32-lane half -> weight DS traffic halved vs r5.
// All 4 P4 rotations from one patch via compile-time permutation (r3-r9).
// r8 lesson: it-loop stays unroll 1; no occupancy floor in launch_bounds.
__global__ __launch_bounds__(512) void mtp_main(const float* __restrict__ x,
                                                const float* __restrict__ kern,
                                                const float* __restrict__ tker,
                                                float* __restrict__ out) {
    __shared__ float4 wlds[NWE];                 // [ccp(8)][q(9)][f(32)] = (t0,t1,k0,k1)
    __shared__ float2 xlds[3][34][8];            // [row][padded col][channel pair]

    const int tid  = threadIdx.x;
    const int bidx = blockIdx.x;                 // (b*64 + i)*2 + half
    const int half = bidx & 1;
    const int i    = (bidx >> 1) & 63;
    const int b    = bidx >> 7;

    // ---- stage weights (coalesced: consecutive tid = consecutive f) ----
    for (int e = tid; e < NWE; e += 512) {
        int f   = e & 31;
        int t   = e >> 5;
        int q   = t % 9;
        int ccp = t / 9;
        int s0 = (q * C_ + ccp * 2 + 0) * F_ + f;
        int s1 = (q * C_ + ccp * 2 + 1) * F_ + f;
        wlds[e] = make_float4(tker[s0], tker[s1], kern[s0], kern[s1]);
    }
    // ---- stage x halo (zero-padded): rows i-1..i+1, cols half*32-1 .. +32 ----
    for (int e = tid; e < NXE; e += 512) {
        int cc4 = e & 3;
        int t   = e >> 2;
        int cl  = t % 34;                        // local padded col
        int di  = t / 34;
        int ro  = i + di - 1;
        int co  = half * 32 + cl - 1;
        float4 v = make_float4(0.f, 0.f, 0.f, 0.f);
        if (ro >= 0 && ro < H_ && co >= 0 && co < W_)
            v = *reinterpret_cast<const float4*>(
                    x + ((b * H_ + ro) * W_ + co) * C_ + cc4 * 4);
        *reinterpret_cast<float4*>(&xlds[di][cl][cc4 * 2]) = v;
    }
    __syncthreads();

    const int lane = tid & 63;
    const int f    = lane & 31;
    const int g    = lane >> 5;                  // channel-group half
    const int w    = tid >> 6;                   // wave 0..7
    const int w4   = w << 2;                     // strip base (padded-local col)

    float acc[4][4];                             // [px][r] partial over 8 channels
    #pragma unroll
    for (int px = 0; px < 4; ++px)
        #pragma unroll
        for (int r = 0; r < 4; ++r) acc[px][r] = 0.f;

    const int wbase = g * (4 * 9 * F_) + f;      // float4-entry index base

    #pragma unroll 1
    for (int it = 0; it < 4; ++it) {             // 4 channel-pairs of this half
        const int pidx = g * 4 + it;             // this lane's channel pair

        // weights: 9 ds_read_b128; halves read different ccp -> no broadcast waste
        float4 wq[9];
        #pragma unroll
        for (int q = 0; q < 9; ++q)
            wq[q] = wlds[wbase + (it * 9 + q) * F_];

        // x halo from LDS: 3 rows x 6 cols float2 (2 distinct addrs/wave each)
        float2 xh[3][6];
        #pragma unroll
        for (int dr = 0; dr < 3; ++dr)
            #pragma unroll
            for (int lc = 0; lc < 6; ++lc)
                xh[dr][lc] = xlds[dr][w4 + lc][pidx];

        #pragma unroll
        for (int px = 0; px < 4; ++px) {
            #pragma unroll
            for (int r = 0; r < 4; ++r) {
                float z0[9], z1[9];
                #pragma unroll
                for (int q = 0; q < 9; ++q) {
                    const int a = q / 3, bq = q % 3;
                    int di, dj;
                    switch (r) {   // x position = rot_r^{-1}(weight position q)
                        case 0:  di = a;      dj = bq;     break;
                        case 1:  di = 2 - bq; dj = a;      break;
                        case 2:  di = 2 - a;  dj = 2 - bq; break;
                        default: di = bq;     dj = 2 - a;  break;
                    }
                    const float2 xv = xh[di][px + dj];
                    z0[q] = fmaf(xv.x, wq[q].x, wq[q].z);
                    z1[q] = fmaf(xv.y, wq[q].y, wq[q].w);
                }
                float m0 = fmaxf(fmaxf(fmaxf(z0[0], z0[1]), z0[2]),
                           fmaxf(fmaxf(fmaxf(z0[3], z0[4]), z0[5]),
                                 fmaxf(fmaxf(z0[6], z0[7]), z0[8])));
                float m1 = fmaxf(fmaxf(fmaxf(z1[0], z1[1]), z1[2]),
                           fmaxf(fmaxf(fmaxf(z1[3], z1[4]), z1[5]),
                                 fmaxf(fmaxf(z1[6], z1[7]), z1[8])));
                acc[px][r] += m0 + m1;
            }
        }
    }

    // ---- cross-half reduce: total = (ch 0-7 partial) + (ch 8-15 partial)
    float tot[4][4];
    #pragma unroll
    for (int px = 0; px < 4; ++px)
        #pragma unroll
        for (int r = 0; r < 4; ++r)
            tot[px][r] = acc[px][r] + __shfl_xor(acc[px][r], 32, 64);

    // ---- store: per (r,slot) lane writes px = slot*2 + g -> 256B contiguous.
    // Constant-index ternary (not tot[slot*2+g]) to avoid scratch (dyn-index trap).
    const int jg = half * 32 + w4 + g;
    #pragma unroll
    for (int r = 0; r < 4; ++r) {
        float* op = out + ((((b * 4 + r) * H_ + i) * W_ + jg) * F_ + f);
        float v0 = g ? tot[1][r] : tot[0][r];
        float v1 = g ? tot[3][r] : tot[2][r];
        op[0]      = v0;
        op[2 * F_] = v1;
    }
}

extern "C" void kernel_launch(void* const* d_in, const int* in_sizes, int n_in,
                              void* d_out, int out_size, void* d_ws, size_t ws_size,
                              hipStream_t stream) {
    const float* x    = (const float*)d_in[0];
    const float* kern = (const float*)d_in[1];
    const float* tker = (const float*)d_in[2];
    float* out = (float*)d_out;

    hipLaunchKernelGGL(mtp_main, dim3(B_ * H_ * 2), dim3(512), 0, stream,
                       x, kern, tker, out);
}